// Round 13
// baseline (254.648 us; speedup 1.0000x reference)
//
#include <hip/hip_runtime.h>
#include <float.h>
#include <math.h>

#define LEAK 0.2f
#define EPS 1e-5f

__device__ __forceinline__ float lrelu(float v){ return v > 0.f ? v : LEAK*v; }

__device__ __forceinline__ void ln_lrelu16(float* h, const float* __restrict__ g, const float* __restrict__ be){
  float mu = 0.f;
#pragma unroll
  for (int o=0;o<16;o++) mu += h[o];
  mu *= 0.0625f;
  float var = 0.f;
#pragma unroll
  for (int o=0;o<16;o++){ float d = h[o]-mu; var += d*d; }
  var *= 0.0625f;
  float rs = 1.0f / sqrtf(var + EPS);
#pragma unroll
  for (int o=0;o<16;o++){ float v = (h[o]-mu)*rs*g[o] + be[o]; h[o] = lrelu(v); }
}

// ---- packed top-k keys: ordered-uint(distance) with 10 index bits in the LSBs.
#define KNN_SENT 0xFF7FFC00u   // enc_key(FLT_MAX, 0): finite, larger than any real key
__device__ __forceinline__ unsigned enc_key(float d, int n){
  unsigned u = __float_as_uint(d);
  u ^= (unsigned)(((int)u) >> 31) | 0x80000000u;   // total-order transform
  return (u & ~1023u) | (unsigned)n;
}
__device__ __forceinline__ float dec_key(unsigned k){
  unsigned u = k ^ ((unsigned)(~(((int)k) >> 31)) | 0x80000000u);
  return __uint_as_float(u);
}

__device__ __forceinline__ unsigned med3u(unsigned a, unsigned b, unsigned c){
  unsigned d;
  asm("v_med3_u32 %0, %1, %2, %3" : "=v"(d) : "v"(a), "v"(b), "v"(c));
  return d;
}

// Insert into ASCENDING sorted dk[16], dropping the max.
// new[j] = median(old[j-1], old[j], key): computed DOWNWARD so old[j-1] is
// still unmodified -> 16 independent v_med3_u32 (1 VALU/slot, no serial chain).
// key >= dk[15] is a mathematical no-op (self-reject); keys unique (index LSBs).
__device__ __forceinline__ void ins_sorted(unsigned (&dk)[16], unsigned key){
#pragma unroll
  for (int j=15;j>0;--j) dk[j] = med3u(dk[j-1], dk[j], key);
  dk[0] = key < dk[0] ? key : dk[0];
}

// KNN top-16 body (r8/r10 measured optimum: ~72.5 us @ ~100% VALUBusy --
// structurally closed).  Candidates staged DIRECTLY from pc (x,y,z + inline
// |p|^2; prep kernel deleted) -- identical expression in both variants so
// keys stay consistent.  Chunk 0 = 32 unconditional inserts + 32 via
// single-u32 flag/drain; chunks 1.. = u64 flag+drain with per-64 Tf refresh.
// Merge: log-tree, final level reversed elementwise min.
template<int QS, int CS, int NQTOT, int NQ, int SPLIT, int NCAND>
__device__ __forceinline__ void knn_body(unsigned* md, float4* scand,
    const float* __restrict__ pc, int bid, int* __restrict__ idx_out)
{
  constexpr int NC = NCAND / SPLIT;                // candidates per thread
  constexpr int QG = NQTOT / NQ;                   // blocks per batch
  constexpr int W  = SPLIT*NQ;                     // md width
  constexpr int QSL = QS / CS;                     // query stride in staged space
  const int b = bid / QG, qg = bid % QG;
  const int tid = threadIdx.x;
  const int m = tid & (NQ-1), s = tid / NQ;        // s is wave-uniform (NQ % 64 == 0)
  const int mg = qg*NQ + m;                        // global query id
  const float* __restrict__ pcb = pc + b*3072;

  for (int i = tid; i < NCAND; i += NQ*SPLIT){
    const int n = i*CS;
    const float x = pcb[n], y = pcb[1024+n], z = pcb[2048+n];
    scand[i] = make_float4(x, y, z, fmaf(x,x, fmaf(y,y, z*z)));
  }
  __syncthreads();

  const float4 qv = scand[mg*QSL];
  const float qx2=-2.f*qv.x, qy2=-2.f*qv.y, qz2=-2.f*qv.z;
  const int n0u = __builtin_amdgcn_readfirstlane(s*NC);   // uniform candidate base

  unsigned dk[16];
#pragma unroll
  for (int j=0;j<16;j++) dk[j] = KNN_SENT;

  // fill: first 32 candidates unconditional (no flag, no divergence).
#pragma unroll 8
  for (int t=0;t<32;t++){
    float4 c = scand[n0u+t];
    float d = fmaf(c.x,qx2, fmaf(c.y,qy2, fmaf(c.z,qz2, c.w)));
    ins_sorted(dk, enc_key(d, n0u+t));
  }
  float Tf = dec_key(dk[15]);

  // rest of chunk 0 (t=32..63): single u32 flag+drain.
  {
    unsigned m32 = 0u;
#pragma unroll 8
    for (int t=32;t<64;t++){
      float4 c = scand[n0u+t];
      float d = fmaf(c.x,qx2, fmaf(c.y,qy2, fmaf(c.z,qz2, c.w)));
      if (d < Tf) m32 |= (1u<<(t-32));
    }
    while (m32){
      const int t = __builtin_ctz(m32) + 32;
      m32 &= m32-1u;
      float4 c = scand[n0u+t];
      float d = fmaf(c.x,qx2, fmaf(c.y,qy2, fmaf(c.z,qz2, c.w)));
      ins_sorted(dk, enc_key(d, n0u+t));
    }
    Tf = dec_key(dk[15]);
  }

  for (int ch=1; ch<NC/64; ch++){
    const int cb0u = n0u + ch*64;                  // uniform
    unsigned long long msk = 0ull;
#pragma unroll 16
    for (int t=0;t<64;t++){
      float4 c = scand[cb0u+t];
      float d = fmaf(c.x,qx2, fmaf(c.y,qy2, fmaf(c.z,qz2, c.w)));
      if (d < Tf) msk |= (1ull<<t);
    }
    while (msk){
      const int t = __builtin_ctzll(msk);
      msk &= msk-1ull;
      float4 c = scand[cb0u+t];
      float d = fmaf(c.x,qx2, fmaf(c.y,qy2, fmaf(c.z,qz2, c.w)));
      ins_sorted(dk, enc_key(d, cb0u+t));
    }
    Tf = dec_key(dk[15]);
  }

  // ---- log-tree merge across splits ----
  if constexpr (SPLIT > 1){
    if (s > 0){
      const int col = s*NQ + m;
#pragma unroll
      for (int j=0;j<16;j++) md[j*W + col] = dk[j];
    }
#pragma unroll
    for (int step = SPLIT/2; step > 1; step >>= 1){
      __syncthreads();
      if (s < step){
        const int col2 = (s+step)*NQ + m;
#pragma unroll
        for (int j=0;j<16;j++) ins_sorted(dk, md[j*W + col2]);
        if (s > 0){
          const int col = s*NQ + m;
#pragma unroll
          for (int j=0;j<16;j++) md[j*W + col] = dk[j];
        }
      }
    }
    __syncthreads();
    if (s != 0) return;
    // final: both lists sorted ascending -> 16 smallest of union is
    // elementwise min with the other list reversed (result unsorted - fine).
    const int col2 = NQ + m;
#pragma unroll
    for (int j=0;j<16;j++){
      unsigned o = md[(15-j)*W + col2];
      dk[j] = o < dk[j] ? o : dk[j];
    }
  }

  int ik[16];
#pragma unroll
  for (int j=0;j<16;j++) ik[j] = (int)(dk[j] & 1023u);
  int4* op = (int4*)(idx_out + (b*NQTOT + mg)*16);
  op[0] = make_int4(ik[0],ik[1],ik[2],ik[3]);
  op[1] = make_int4(ik[4],ik[5],ik[6],ik[7]);
  op[2] = make_int4(ik[8],ik[9],ik[10],ik[11]);
  op[3] = make_int4(ik[12],ik[13],ik[14],ik[15]);
}

// Fused knn, r8 geometry: 1024-thr blocks; blocks 0..255 = knn1 (512 q,
// SPLIT=2), blocks 256..511 = knn2 (128 q, SPLIT=8).  80 KB union -> 2
// blocks/CU, 32 waves/CU; measured ~76% occ / ~100% VALUBusy.
__global__ __attribute__((amdgpu_flat_work_group_size(1024,1024), amdgpu_waves_per_eu(4,8)))
void knn_fused_kernel(const float* __restrict__ pc,
                      int* __restrict__ idx1, int* __restrict__ idx2)
{
  __shared__ __align__(16) char smem[81920];       // 64 KB md + 16 KB scand
  unsigned* md = (unsigned*)smem;
  if (blockIdx.x < 256){
    float4* scand = (float4*)(smem + 65536);
    knn_body<2,1,512,512,2,1024>(md, scand, pc, blockIdx.x, idx1);
  } else {
    float4* scand = (float4*)(smem + 65536);
    knn_body<8,2,128,128,8,512>(md, scand, pc, blockIdx.x - 256, idx2);
  }
}

// pointconv1 (19->32, maxpool over 16 NN), DOUBLE-FACTORIZED:
//   h[o] = PP_j[o] - Q_m[o],
//   PP_j = Wb + f_j.W[3:19] + p_j.W[0:3]  (phase 0),  Q_m = q_m.W[0:3].
// feats MLP (3->16->16, LN+lrelu) computed INLINE in phase 0 from pc
// (prep kernel + 32 MB feats round-trip deleted; extra VALU measured off
// the critical path r10/r11).  Inner body 1 SUB + 1 MAX.  P transposed in
// LDS (sPT[o][j], b32 gather).  2 o-halves/batch, 64 KB -> 2 blocks/CU.
// Epilogue: partial fs (feat2 fuses lrelu+sum).
__global__ __attribute__((amdgpu_flat_work_group_size(512,512), amdgpu_waves_per_eu(4,4)))
void feat1_kernel(const float* __restrict__ pc, const int* __restrict__ idx1,
    const float* __restrict__ W0, const float* __restrict__ b0, const float* __restrict__ g0, const float* __restrict__ be0,
    const float* __restrict__ W1, const float* __restrict__ b1, const float* __restrict__ g1, const float* __restrict__ be1,
    const float* __restrict__ W, const float* __restrict__ Wb,
    const float* __restrict__ Ws,
    float* __restrict__ p1part)
{
  __shared__ float sPT[16*1024];                   // 64 KB, o-major
  const int bx = blockIdx.x;
  const int b = bx >> 1, ob = bx & 1;              // batch, o-half
  const int ob16 = ob*16;
  const int tid = threadIdx.x;
  const float* __restrict__ pb = pc + b*3072;

  // ---- phase 0: feats MLP + PP_j over this block's 16 o's, 2 pts/thread ----
#pragma unroll
  for (int i=0;i<2;i++){
    const int j = tid + i*512;
    const float x = pb[j], y = pb[1024+j], z = pb[2048+j];
    float h[16];
#pragma unroll
    for (int o=0;o<16;o++) h[o] = b0[o] + x*W0[o] + y*W0[16+o] + z*W0[32+o];
    ln_lrelu16(h, g0, be0);
    float f[16];
#pragma unroll
    for (int o=0;o<16;o++){
      float s = b1[o];
#pragma unroll
      for (int c=0;c<16;c++) s += h[c]*W1[c*16+o];
      f[o] = s;
    }
    ln_lrelu16(f, g1, be1);
#pragma unroll
    for (int o4=0;o4<4;o4++){
      float4 s = *(const float4*)(Wb + ob16 + o4*4);   // bias folded in
      { float4 wa = *(const float4*)(W +       ob16 + o4*4);   // xyz rows folded
        float4 wb = *(const float4*)(W + 32  + ob16 + o4*4);
        float4 wc = *(const float4*)(W + 64  + ob16 + o4*4);
        s.x = fmaf(x,wa.x, fmaf(y,wb.x, fmaf(z,wc.x, s.x)));
        s.y = fmaf(x,wa.y, fmaf(y,wb.y, fmaf(z,wc.y, s.y)));
        s.z = fmaf(x,wa.z, fmaf(y,wb.z, fmaf(z,wc.z, s.z)));
        s.w = fmaf(x,wa.w, fmaf(y,wb.w, fmaf(z,wc.w, s.w))); }
#pragma unroll
      for (int c=0;c<16;c++){
        float4 w = *(const float4*)(W + (3+c)*32 + ob16 + o4*4);  // uniform
        s.x = fmaf(f[c], w.x, s.x);
        s.y = fmaf(f[c], w.y, s.y);
        s.z = fmaf(f[c], w.z, s.z);
        s.w = fmaf(f[c], w.w, s.w);
      }
      sPT[(o4*4+0)*1024 + j] = s.x;                // coalesced column writes
      sPT[(o4*4+1)*1024 + j] = s.y;
      sPT[(o4*4+2)*1024 + j] = s.z;
      sPT[(o4*4+3)*1024 + j] = s.w;
    }
  }
  __syncthreads();

  // ---- main: per query, Q_m once, then 16 neighbors x 16 outputs ----
  const int m = tid;
  const float qx = pb[2*m], qy = pb[1024+2*m], qz = pb[2048+2*m];
  float Q[16];
#pragma unroll
  for (int i=0;i<4;i++){
    float4 a = *(const float4*)(W +       ob16 + i*4);
    float4 bb= *(const float4*)(W + 32  + ob16 + i*4);
    float4 cc= *(const float4*)(W + 64  + ob16 + i*4);
    Q[i*4+0] = fmaf(qx,a.x, fmaf(qy,bb.x, qz*cc.x));
    Q[i*4+1] = fmaf(qx,a.y, fmaf(qy,bb.y, qz*cc.y));
    Q[i*4+2] = fmaf(qx,a.z, fmaf(qy,bb.z, qz*cc.z));
    Q[i*4+3] = fmaf(qx,a.w, fmaf(qy,bb.w, qz*cc.w));
  }
  int idxr[16];
  { const int4* ip = (const int4*)(idx1 + (b*512+m)*16);
    int4 a=ip[0], b2=ip[1], c2=ip[2], d2=ip[3];
    idxr[0]=a.x; idxr[1]=a.y; idxr[2]=a.z; idxr[3]=a.w;
    idxr[4]=b2.x; idxr[5]=b2.y; idxr[6]=b2.z; idxr[7]=b2.w;
    idxr[8]=c2.x; idxr[9]=c2.y; idxr[10]=c2.z; idxr[11]=c2.w;
    idxr[12]=d2.x; idxr[13]=d2.y; idxr[14]=d2.z; idxr[15]=d2.w; }

  float acc[16];
#pragma unroll
  for (int o=0;o<16;o++) acc[o] = -FLT_MAX;

#pragma unroll 4
  for (int k=0;k<16;k++){
    const int j = idxr[k];
    const float* pj = sPT + j;                     // one vaddr, 16 imm offsets
#pragma unroll
    for (int o=0;o<16;o++)
      acc[o] = fmaxf(acc[o], pj[o*1024] - Q[o]);   // 1 sub + 1 max
  }

  float fsacc[8] = {0.f,0.f,0.f,0.f,0.f,0.f,0.f,0.f};
#pragma unroll
  for (int o=0;o<16;o++){
    const float a = fmaxf(acc[o], 0.2f*acc[o]);    // lrelu once per output
    float4 u = *(const float4*)(Ws + (ob16+o)*8);  // uniform -> s_load
    float4 v = *(const float4*)(Ws + (ob16+o)*8 + 4);
    fsacc[0] = fmaf(a, u.x, fsacc[0]);
    fsacc[1] = fmaf(a, u.y, fsacc[1]);
    fsacc[2] = fmaf(a, u.z, fsacc[2]);
    fsacc[3] = fmaf(a, u.w, fsacc[3]);
    fsacc[4] = fmaf(a, v.x, fsacc[4]);
    fsacc[5] = fmaf(a, v.y, fsacc[5]);
    fsacc[6] = fmaf(a, v.z, fsacc[6]);
    fsacc[7] = fmaf(a, v.w, fsacc[7]);
  }
  float4* op = (float4*)(p1part + ((b*2+ob)*512 + m)*8);
  op[0] = make_float4(fsacc[0],fsacc[1],fsacc[2],fsacc[3]);
  op[1] = make_float4(fsacc[4],fsacc[5],fsacc[6],fsacc[7]);
}

// pointconv2 (11->128, maxpool over 16 NN), DOUBLE-FACTORIZED, WITH THE
// FINAL @We+be MEAN FUSED via the last-block pattern:
//   h[o] = PP2_j[o] - Q_m[o],  PP2_j = bc + f_j.Wc[3:11] + p_j.Wc[0:3],
//   f_j = lrelu(p1part_half0 + p1part_half1 + bs).
// Each of the batch's 4 o-blocks release-stores its 32-float slice (agent
// scope -- cross-XCD safe) and bumps a per-batch counter; the block seeing
// old==3 acquire-loads all 128 and computes out[b][:].  cnt is ZEROED by a
// stream-ordered hipMemsetAsync in kernel_launch (part of the captured
// graph, re-executed every replay) -- r12's garbage-init let an EARLY block
// win (mod-4 only guarantees uniqueness, not last-ness).  Deterministic:
// fixed summation order over fully-written inputs.
__global__ __attribute__((amdgpu_flat_work_group_size(512,512), amdgpu_waves_per_eu(4,4)))
void feat2_kernel(const float* __restrict__ pc,
    const float* __restrict__ p1part, const int* __restrict__ idx2,
    const float* __restrict__ Wc, const float* __restrict__ bc,
    const float* __restrict__ bs,
    const float* __restrict__ We, const float* __restrict__ beF,
    float* __restrict__ p2red, unsigned int* __restrict__ cnt,
    float* __restrict__ out)
{
  __shared__ float sP2[512*32];                    // 64 KB, swizzled 16B slots
  __shared__ float sred[32];
  __shared__ float sfin[128];
  __shared__ int sLast;
  const int bx = blockIdx.x;                       // 0..1023
  const int b = bx >> 2, ob = bx & 3;              // batch, o-block (32 outputs)
  const int o_base = ob*32;
  const int tid = threadIdx.x;
  const float* __restrict__ pb = pc + b*3072;
  if (tid < 32) sred[tid] = 0.f;

  // ---- phase 0: f_j = lrelu(pa+pb+bs); PP2_j = bc + f_j@Wc[3:11] + p_j@Wc[0:3] ----
  { const float4* __restrict__ pa4 = (const float4*)(p1part + ((b*2+0)*512 + tid)*8);
    const float4* __restrict__ pb4 = (const float4*)(p1part + ((b*2+1)*512 + tid)*8);
    float4 a0 = pa4[0], a1 = pa4[1], c0 = pb4[0], c1 = pb4[1];
    float4 s0 = *(const float4*)(bs), s1 = *(const float4*)(bs+4);
    float f[8];
    f[0]=lrelu(a0.x+c0.x+s0.x); f[1]=lrelu(a0.y+c0.y+s0.y);
    f[2]=lrelu(a0.z+c0.z+s0.z); f[3]=lrelu(a0.w+c0.w+s0.w);
    f[4]=lrelu(a1.x+c1.x+s1.x); f[5]=lrelu(a1.y+c1.y+s1.y);
    f[6]=lrelu(a1.z+c1.z+s1.z); f[7]=lrelu(a1.w+c1.w+s1.w);
    const float cjx = pb[2*tid], cjy = pb[1024+2*tid], cjz = pb[2048+2*tid];
    float* row = sP2 + tid*32;
    const int sw = (tid & 7);
#pragma unroll
    for (int o4=0;o4<8;o4++){
      float4 s = *(const float4*)(bc + o_base + o4*4);   // bias folded in
      { float4 wa = *(const float4*)(Wc +        o_base + o4*4);  // xyz rows
        float4 wb = *(const float4*)(Wc + 128  + o_base + o4*4);
        float4 wc = *(const float4*)(Wc + 256  + o_base + o4*4);
        s.x = fmaf(cjx,wa.x, fmaf(cjy,wb.x, fmaf(cjz,wc.x, s.x)));
        s.y = fmaf(cjx,wa.y, fmaf(cjy,wb.y, fmaf(cjz,wc.y, s.y)));
        s.z = fmaf(cjx,wa.z, fmaf(cjy,wb.z, fmaf(cjz,wc.z, s.z)));
        s.w = fmaf(cjx,wa.w, fmaf(cjy,wb.w, fmaf(cjz,wc.w, s.w))); }
#pragma unroll
      for (int c=0;c<8;c++){
        float4 w = *(const float4*)(Wc + (3+c)*128 + o_base + o4*4); // uniform
        s.x = fmaf(f[c], w.x, s.x);
        s.y = fmaf(f[c], w.y, s.y);
        s.z = fmaf(f[c], w.z, s.z);
        s.w = fmaf(f[c], w.w, s.w);
      }
      *(float4*)(row + ((o4 ^ sw) << 2)) = s;            // swizzled 16B slot
    }
  }
  __syncthreads();

  // ---- main: thread (m = tid>>2, oq = tid&3) -> query m, 8 outputs ----
  const int m = tid >> 2, oq = tid & 3;            // 128 queries x 4 o-quads
  const float qx = pb[8*m], qy = pb[1024+8*m], qz = pb[2048+8*m];
  float Q[8];
  { const int og = o_base + oq*8;
#pragma unroll
    for (int i=0;i<2;i++){
      float4 a = *(const float4*)(Wc +        og + i*4);
      float4 bb= *(const float4*)(Wc + 128  + og + i*4);
      float4 cc= *(const float4*)(Wc + 256  + og + i*4);
      Q[i*4+0] = fmaf(qx,a.x, fmaf(qy,bb.x, qz*cc.x));
      Q[i*4+1] = fmaf(qx,a.y, fmaf(qy,bb.y, qz*cc.y));
      Q[i*4+2] = fmaf(qx,a.z, fmaf(qy,bb.z, qz*cc.z));
      Q[i*4+3] = fmaf(qx,a.w, fmaf(qy,bb.w, qz*cc.w));
    } }
  int idxr[16];
  { const int4* ip = (const int4*)(idx2 + (b*128+m)*16);
    int4 a=ip[0], b2=ip[1], c2=ip[2], d2=ip[3];
    idxr[0]=a.x; idxr[1]=a.y; idxr[2]=a.z; idxr[3]=a.w;
    idxr[4]=b2.x; idxr[5]=b2.y; idxr[6]=b2.z; idxr[7]=b2.w;
    idxr[8]=c2.x; idxr[9]=c2.y; idxr[10]=c2.z; idxr[11]=c2.w;
    idxr[12]=d2.x; idxr[13]=d2.y; idxr[14]=d2.z; idxr[15]=d2.w; }

  float acc[8];
#pragma unroll
  for (int o=0;o<8;o++) acc[o] = -FLT_MAX;

#pragma unroll 4
  for (int k=0;k<16;k++){
    const int j = idxr[k];
    const float* row = sP2 + j*32;
    const int sw = (j & 7);
    float4 p0 = *(const float4*)(row + (((2*oq  ) ^ sw) << 2));
    float4 p1 = *(const float4*)(row + (((2*oq+1) ^ sw) << 2));
    acc[0] = fmaxf(acc[0], p0.x - Q[0]);
    acc[1] = fmaxf(acc[1], p0.y - Q[1]);
    acc[2] = fmaxf(acc[2], p0.z - Q[2]);
    acc[3] = fmaxf(acc[3], p0.w - Q[3]);
    acc[4] = fmaxf(acc[4], p1.x - Q[4]);
    acc[5] = fmaxf(acc[5], p1.y - Q[5]);
    acc[6] = fmaxf(acc[6], p1.z - Q[6]);
    acc[7] = fmaxf(acc[7], p1.w - Q[7]);
  }

  // lrelu once per output, then mean over queries: shfl-reduce the 16 m's in
  // this wave (lane bits 2..5), one atomic per (wave, oq, o).
#pragma unroll
  for (int o=0;o<8;o++){
    float v = fmaxf(acc[o], 0.2f*acc[o]);
    v += __shfl_xor(v, 4);
    v += __shfl_xor(v, 8);
    v += __shfl_xor(v, 16);
    v += __shfl_xor(v, 32);
    if ((threadIdx.x & 60) == 0)                   // lanes 0..3, one per oq
      atomicAdd(&sred[oq*8+o], v);
  }
  __syncthreads();

  // ---- fused final: last block of this batch applies @We + beF, /128 ----
  if (tid < 32)
    __hip_atomic_store(&p2red[b*128 + o_base + tid], sred[tid],
                       __ATOMIC_RELEASE, __HIP_MEMORY_SCOPE_AGENT);
  __syncthreads();                                 // drains stores (vmcnt 0) before tid0 proceeds
  if (tid == 0){
    unsigned old = __hip_atomic_fetch_add(&cnt[b], 1u,
                       __ATOMIC_ACQ_REL, __HIP_MEMORY_SCOPE_AGENT);
    sLast = (old == 3u) ? 1 : 0;                   // cnt zeroed per launch -> truly last
  }
  __syncthreads();
  if (sLast){
    if (tid < 128)
      sfin[tid] = __hip_atomic_load(&p2red[b*128 + tid],
                       __ATOMIC_ACQUIRE, __HIP_MEMORY_SCOPE_AGENT);
    __syncthreads();
    if (tid < 256){
      float s = 0.f;
#pragma unroll 8
      for (int c=0;c<128;c++) s += sfin[c]*We[c*256+tid];
      out[b*256+tid] = beF[tid] + s*0.0078125f;    // mean over 128 queries
    }
  }
}

extern "C" void kernel_launch(void* const* d_in, const int* in_sizes, int n_in,
                              void* d_out, int out_size, void* d_ws, size_t ws_size,
                              hipStream_t stream) {
  (void)in_sizes; (void)n_in; (void)out_size; (void)ws_size;
  const float* pc   = (const float*)d_in[0];
  const float* W0   = (const float*)d_in[1];
  const float* b0   = (const float*)d_in[2];
  const float* g0   = (const float*)d_in[3];
  const float* be0  = (const float*)d_in[4];
  const float* W1   = (const float*)d_in[5];
  const float* b1   = (const float*)d_in[6];
  const float* g1   = (const float*)d_in[7];
  const float* be1  = (const float*)d_in[8];
  const float* pcW  = (const float*)d_in[9];
  const float* pcb  = (const float*)d_in[10];
  const float* Ws   = (const float*)d_in[11];
  const float* bs   = (const float*)d_in[12];
  const float* Wc   = (const float*)d_in[13];
  const float* bc   = (const float*)d_in[14];
  const float* We   = (const float*)d_in[15];
  const float* beF  = (const float*)d_in[16];
  (void)pcb;

  char* ws = (char*)d_ws;
  int*    idx1  = (int*)  ws;                         // 0-8 MB
  int*    idx2  = (int*)  (ws + (8u<<20));            // 8-10 MB
  float*  p1part= (float*)(ws + (10u<<20));           // 10-18 MB
  float*  p2red = (float*)(ws + (18u<<20));           // 128 KB
  unsigned int* cnt = (unsigned int*)(ws + (19u<<20));// 1 KB, zeroed below
  float*  out   = (float*)d_out;

  // Stream-ordered zeroing of the per-batch arrival counters: captured into
  // the graph, so every replay restarts the phase at 0 (r12 bug fix).
  hipMemsetAsync(cnt, 0, 256*sizeof(unsigned int), stream);

  knn_fused_kernel<<<512, 1024, 0, stream>>>(pc, idx1, idx2);
  feat1_kernel<<<512, 512, 0, stream>>>(pc, idx1, W0,b0,g0,be0, W1,b1,g1,be1,
                                        pcW, pcb, Ws, p1part);
  feat2_kernel<<<1024, 512, 0, stream>>>(pc, p1part, idx2, Wc, bc, bs,
                                         We, beF, p2red, cnt, out);
}

// Round 14
// 244.532 us; speedup vs baseline: 1.0414x; 1.0414x over previous
//
#include <hip/hip_runtime.h>
#include <float.h>
#include <math.h>

#define LEAK 0.2f
#define EPS 1e-5f

__device__ __forceinline__ float lrelu(float v){ return v > 0.f ? v : LEAK*v; }

__device__ __forceinline__ void ln_lrelu16(float* h, const float* __restrict__ g, const float* __restrict__ be){
  float mu = 0.f;
#pragma unroll
  for (int o=0;o<16;o++) mu += h[o];
  mu *= 0.0625f;
  float var = 0.f;
#pragma unroll
  for (int o=0;o<16;o++){ float d = h[o]-mu; var += d*d; }
  var *= 0.0625f;
  float rs = 1.0f / sqrtf(var + EPS);
#pragma unroll
  for (int o=0;o<16;o++){ float v = (h[o]-mu)*rs*g[o] + be[o]; h[o] = lrelu(v); }
}

// Stage 1: per-point candidate float4 (x,y,z,|p|^2) + 3->16->16 MLP w/ LN+lrelu.
// RESTORED (r13 lesson: inlining this into knn doubled knn's VGPR 32->64,
// occupancy 76->40%, +21 us; into feat1's phase 0 cost more than the saved
// launches).  Cheap kernel, keeps the hot kernels' codegen clean.
__global__ __launch_bounds__(256) void prep_kernel(const float* __restrict__ pc,
    const float* __restrict__ W0, const float* __restrict__ b0, const float* __restrict__ g0, const float* __restrict__ be0,
    const float* __restrict__ W1, const float* __restrict__ b1, const float* __restrict__ g1, const float* __restrict__ be1,
    float4* __restrict__ cand, float* __restrict__ feats)
{
  const int p = blockIdx.x*256 + threadIdx.x;      // 0 .. 256*1024-1
  const int b = p >> 10, n = p & 1023;
  const float* base = pc + b*3072;
  const float x = base[n], y = base[1024+n], z = base[2048+n];
  cand[p] = make_float4(x, y, z, x*x + y*y + z*z);
  float h[16];
#pragma unroll
  for (int o=0;o<16;o++) h[o] = b0[o] + x*W0[o] + y*W0[16+o] + z*W0[32+o];
  ln_lrelu16(h, g0, be0);
  float h2[16];
#pragma unroll
  for (int o=0;o<16;o++){
    float s = b1[o];
#pragma unroll
    for (int c=0;c<16;c++) s += h[c]*W1[c*16+o];
    h2[o] = s;
  }
  ln_lrelu16(h2, g1, be1);
  float4* fo = (float4*)(feats + p*16);
  fo[0] = make_float4(h2[0],h2[1],h2[2],h2[3]);
  fo[1] = make_float4(h2[4],h2[5],h2[6],h2[7]);
  fo[2] = make_float4(h2[8],h2[9],h2[10],h2[11]);
  fo[3] = make_float4(h2[12],h2[13],h2[14],h2[15]);
}

// ---- packed top-k keys: ordered-uint(distance) with 10 index bits in the LSBs.
#define KNN_SENT 0xFF7FFC00u   // enc_key(FLT_MAX, 0): finite, larger than any real key
__device__ __forceinline__ unsigned enc_key(float d, int n){
  unsigned u = __float_as_uint(d);
  u ^= (unsigned)(((int)u) >> 31) | 0x80000000u;   // total-order transform
  return (u & ~1023u) | (unsigned)n;
}
__device__ __forceinline__ float dec_key(unsigned k){
  unsigned u = k ^ ((unsigned)(~(((int)k) >> 31)) | 0x80000000u);
  return __uint_as_float(u);
}

__device__ __forceinline__ unsigned med3u(unsigned a, unsigned b, unsigned c){
  unsigned d;
  asm("v_med3_u32 %0, %1, %2, %3" : "=v"(d) : "v"(a), "v"(b), "v"(c));
  return d;
}

// Insert into ASCENDING sorted dk[16], dropping the max.
// new[j] = median(old[j-1], old[j], key): computed DOWNWARD so old[j-1] is
// still unmodified -> 16 independent v_med3_u32 (1 VALU/slot, no serial chain).
// key >= dk[15] is a mathematical no-op (self-reject); keys unique (index LSBs).
__device__ __forceinline__ void ins_sorted(unsigned (&dk)[16], unsigned key){
#pragma unroll
  for (int j=15;j>0;--j) dk[j] = med3u(dk[j-1], dk[j], key);
  dk[0] = key < dk[0] ? key : dk[0];
}

// KNN top-16 body (r8/r10 measured optimum: ~72.5 us @ ~100% VALUBusy,
// VGPR 32, occ 76% -- structurally closed; reads the prep'd cand float4s).
// Candidates staged in LDS; chunk 0 = 32 unconditional inserts + 32 via
// single-u32 flag/drain; chunks 1.. = u64 flag+drain with per-64 Tf refresh.
// Merge: log-tree of ins-merges, final level via reversed elementwise min.
template<int QS, int CS, int NQTOT, int NQ, int SPLIT, int NCAND>
__device__ __forceinline__ void knn_body(unsigned* md, float4* scand,
    const float4* __restrict__ cand, int bid, int* __restrict__ idx_out)
{
  constexpr int NC = NCAND / SPLIT;                // candidates per thread
  constexpr int QG = NQTOT / NQ;                   // blocks per batch
  constexpr int W  = SPLIT*NQ;                     // md width
  constexpr int QSL = QS / CS;                     // query stride in staged space
  const int b = bid / QG, qg = bid % QG;
  const int tid = threadIdx.x;
  const int m = tid & (NQ-1), s = tid / NQ;        // s is wave-uniform (NQ % 64 == 0)
  const int mg = qg*NQ + m;                        // global query id
  const float4* __restrict__ cb = cand + b*1024;

  for (int i = tid; i < NCAND; i += NQ*SPLIT)
    scand[i] = cb[i*CS];
  __syncthreads();

  const float4 qv = scand[mg*QSL];
  const float qx2=-2.f*qv.x, qy2=-2.f*qv.y, qz2=-2.f*qv.z;
  const int n0u = __builtin_amdgcn_readfirstlane(s*NC);   // uniform candidate base

  unsigned dk[16];
#pragma unroll
  for (int j=0;j<16;j++) dk[j] = KNN_SENT;

  // fill: first 32 candidates unconditional (no flag, no divergence).
#pragma unroll 8
  for (int t=0;t<32;t++){
    float4 c = scand[n0u+t];
    float d = fmaf(c.x,qx2, fmaf(c.y,qy2, fmaf(c.z,qz2, c.w)));
    ins_sorted(dk, enc_key(d, n0u+t));
  }
  float Tf = dec_key(dk[15]);

  // rest of chunk 0 (t=32..63): single u32 flag+drain.
  {
    unsigned m32 = 0u;
#pragma unroll 8
    for (int t=32;t<64;t++){
      float4 c = scand[n0u+t];
      float d = fmaf(c.x,qx2, fmaf(c.y,qy2, fmaf(c.z,qz2, c.w)));
      if (d < Tf) m32 |= (1u<<(t-32));
    }
    while (m32){
      const int t = __builtin_ctz(m32) + 32;
      m32 &= m32-1u;
      float4 c = scand[n0u+t];
      float d = fmaf(c.x,qx2, fmaf(c.y,qy2, fmaf(c.z,qz2, c.w)));
      ins_sorted(dk, enc_key(d, n0u+t));
    }
    Tf = dec_key(dk[15]);
  }

  for (int ch=1; ch<NC/64; ch++){
    const int cb0u = n0u + ch*64;                  // uniform
    unsigned long long msk = 0ull;
#pragma unroll 16
    for (int t=0;t<64;t++){
      float4 c = scand[cb0u+t];
      float d = fmaf(c.x,qx2, fmaf(c.y,qy2, fmaf(c.z,qz2, c.w)));
      if (d < Tf) msk |= (1ull<<t);
    }
    while (msk){
      const int t = __builtin_ctzll(msk);
      msk &= msk-1ull;
      float4 c = scand[cb0u+t];
      float d = fmaf(c.x,qx2, fmaf(c.y,qy2, fmaf(c.z,qz2, c.w)));
      ins_sorted(dk, enc_key(d, cb0u+t));
    }
    Tf = dec_key(dk[15]);
  }

  // ---- log-tree merge across splits ----
  if constexpr (SPLIT > 1){
    if (s > 0){
      const int col = s*NQ + m;
#pragma unroll
      for (int j=0;j<16;j++) md[j*W + col] = dk[j];
    }
#pragma unroll
    for (int step = SPLIT/2; step > 1; step >>= 1){
      __syncthreads();
      if (s < step){
        const int col2 = (s+step)*NQ + m;
#pragma unroll
        for (int j=0;j<16;j++) ins_sorted(dk, md[j*W + col2]);
        if (s > 0){
          const int col = s*NQ + m;
#pragma unroll
          for (int j=0;j<16;j++) md[j*W + col] = dk[j];
        }
      }
    }
    __syncthreads();
    if (s != 0) return;
    // final: both lists sorted ascending -> 16 smallest of union is
    // elementwise min with the other list reversed (result unsorted - fine).
    const int col2 = NQ + m;
#pragma unroll
    for (int j=0;j<16;j++){
      unsigned o = md[(15-j)*W + col2];
      dk[j] = o < dk[j] ? o : dk[j];
    }
  }

  int ik[16];
#pragma unroll
  for (int j=0;j<16;j++) ik[j] = (int)(dk[j] & 1023u);
  int4* op = (int4*)(idx_out + (b*NQTOT + mg)*16);
  op[0] = make_int4(ik[0],ik[1],ik[2],ik[3]);
  op[1] = make_int4(ik[4],ik[5],ik[6],ik[7]);
  op[2] = make_int4(ik[8],ik[9],ik[10],ik[11]);
  op[3] = make_int4(ik[12],ik[13],ik[14],ik[15]);
}

// Fused knn, r8 geometry: 1024-thr blocks; blocks 0..255 = knn1 (512 q,
// SPLIT=2), blocks 256..511 = knn2 (128 q, SPLIT=8).  80 KB union -> 2
// blocks/CU, 32 waves/CU; measured ~76% occ / ~100% VALUBusy.
__global__ __attribute__((amdgpu_flat_work_group_size(1024,1024), amdgpu_waves_per_eu(4,8)))
void knn_fused_kernel(const float4* __restrict__ cand,
                      int* __restrict__ idx1, int* __restrict__ idx2)
{
  __shared__ __align__(16) char smem[81920];       // 64 KB md + 16 KB scand
  unsigned* md = (unsigned*)smem;
  if (blockIdx.x < 256){
    float4* scand = (float4*)(smem + 65536);
    knn_body<2,1,512,512,2,1024>(md, scand, cand, blockIdx.x, idx1);
  } else {
    float4* scand = (float4*)(smem + 65536);
    knn_body<8,2,128,128,8,512>(md, scand, cand, blockIdx.x - 256, idx2);
  }
}

// pointconv1 (19->32, maxpool over 16 NN), DOUBLE-FACTORIZED (r11 proven):
//   h[o] = PP_j[o] - Q_m[o],
//   PP_j = Wb + f_j.W[3:19] + p_j.W[0:3]  (phase 0),  Q_m = q_m.W[0:3].
// Inner body 1 SUB + 1 MAX.  P transposed in LDS (sPT[o][j], b32 gather).
// 2 o-halves/batch, 64 KB -> 2 blocks/CU.  Epilogue: partial fs
// (feat2 fuses lrelu(p0+p1+bs)).
__global__ __attribute__((amdgpu_flat_work_group_size(512,512), amdgpu_waves_per_eu(4,4)))
void feat1_kernel(const float4* __restrict__ cand,
    const float* __restrict__ feats, const int* __restrict__ idx1,
    const float* __restrict__ W, const float* __restrict__ Wb,
    const float* __restrict__ Ws,
    float* __restrict__ p1part)
{
  __shared__ float sPT[16*1024];                   // 64 KB, o-major
  const int bx = blockIdx.x;
  const int b = bx >> 1, ob = bx & 1;              // batch, o-half
  const int ob16 = ob*16;
  const int tid = threadIdx.x;
  const float4* __restrict__ cb = cand + b*1024;
  const float4* __restrict__ fb4 = (const float4*)(feats + b*16384);

  // ---- phase 0: PP_j over this block's 16 o's, 2 points per thread ----
#pragma unroll
  for (int i=0;i<2;i++){
    const int j = tid + i*512;
    float4 cj = cb[j];                             // point xyz (w unused)
    float4 f0 = fb4[j*4+0], f1 = fb4[j*4+1], f2 = fb4[j*4+2], f3 = fb4[j*4+3];
    float f[16] = {f0.x,f0.y,f0.z,f0.w, f1.x,f1.y,f1.z,f1.w,
                   f2.x,f2.y,f2.z,f2.w, f3.x,f3.y,f3.z,f3.w};
#pragma unroll
    for (int o4=0;o4<4;o4++){
      float4 s = *(const float4*)(Wb + ob16 + o4*4);   // bias folded in
      { float4 wa = *(const float4*)(W +       ob16 + o4*4);   // xyz rows folded
        float4 wb = *(const float4*)(W + 32  + ob16 + o4*4);
        float4 wc = *(const float4*)(W + 64  + ob16 + o4*4);
        s.x = fmaf(cj.x,wa.x, fmaf(cj.y,wb.x, fmaf(cj.z,wc.x, s.x)));
        s.y = fmaf(cj.x,wa.y, fmaf(cj.y,wb.y, fmaf(cj.z,wc.y, s.y)));
        s.z = fmaf(cj.x,wa.z, fmaf(cj.y,wb.z, fmaf(cj.z,wc.z, s.z)));
        s.w = fmaf(cj.x,wa.w, fmaf(cj.y,wb.w, fmaf(cj.z,wc.w, s.w))); }
#pragma unroll
      for (int c=0;c<16;c++){
        float4 w = *(const float4*)(W + (3+c)*32 + ob16 + o4*4);  // uniform
        s.x = fmaf(f[c], w.x, s.x);
        s.y = fmaf(f[c], w.y, s.y);
        s.z = fmaf(f[c], w.z, s.z);
        s.w = fmaf(f[c], w.w, s.w);
      }
      sPT[(o4*4+0)*1024 + j] = s.x;                // coalesced column writes
      sPT[(o4*4+1)*1024 + j] = s.y;
      sPT[(o4*4+2)*1024 + j] = s.z;
      sPT[(o4*4+3)*1024 + j] = s.w;
    }
  }
  __syncthreads();

  // ---- main: per query, Q_m once, then 16 neighbors x 16 outputs ----
  const int m = tid;
  const float4 qv = cb[2*m];                       // query xyz
  float Q[16];
#pragma unroll
  for (int i=0;i<4;i++){
    float4 a = *(const float4*)(W +       ob16 + i*4);
    float4 bb= *(const float4*)(W + 32  + ob16 + i*4);
    float4 cc= *(const float4*)(W + 64  + ob16 + i*4);
    Q[i*4+0] = fmaf(qv.x,a.x, fmaf(qv.y,bb.x, qv.z*cc.x));
    Q[i*4+1] = fmaf(qv.x,a.y, fmaf(qv.y,bb.y, qv.z*cc.y));
    Q[i*4+2] = fmaf(qv.x,a.z, fmaf(qv.y,bb.z, qv.z*cc.z));
    Q[i*4+3] = fmaf(qv.x,a.w, fmaf(qv.y,bb.w, qv.z*cc.w));
  }
  int idxr[16];
  { const int4* ip = (const int4*)(idx1 + (b*512+m)*16);
    int4 a=ip[0], b2=ip[1], c2=ip[2], d2=ip[3];
    idxr[0]=a.x; idxr[1]=a.y; idxr[2]=a.z; idxr[3]=a.w;
    idxr[4]=b2.x; idxr[5]=b2.y; idxr[6]=b2.z; idxr[7]=b2.w;
    idxr[8]=c2.x; idxr[9]=c2.y; idxr[10]=c2.z; idxr[11]=c2.w;
    idxr[12]=d2.x; idxr[13]=d2.y; idxr[14]=d2.z; idxr[15]=d2.w; }

  float acc[16];
#pragma unroll
  for (int o=0;o<16;o++) acc[o] = -FLT_MAX;

#pragma unroll 4
  for (int k=0;k<16;k++){
    const int j = idxr[k];
    const float* pj = sPT + j;                     // one vaddr, 16 imm offsets
#pragma unroll
    for (int o=0;o<16;o++)
      acc[o] = fmaxf(acc[o], pj[o*1024] - Q[o]);   // 1 sub + 1 max
  }

  float fsacc[8] = {0.f,0.f,0.f,0.f,0.f,0.f,0.f,0.f};
#pragma unroll
  for (int o=0;o<16;o++){
    const float a = fmaxf(acc[o], 0.2f*acc[o]);    // lrelu once per output
    float4 u = *(const float4*)(Ws + (ob16+o)*8);  // uniform -> s_load
    float4 v = *(const float4*)(Ws + (ob16+o)*8 + 4);
    fsacc[0] = fmaf(a, u.x, fsacc[0]);
    fsacc[1] = fmaf(a, u.y, fsacc[1]);
    fsacc[2] = fmaf(a, u.z, fsacc[2]);
    fsacc[3] = fmaf(a, u.w, fsacc[3]);
    fsacc[4] = fmaf(a, v.x, fsacc[4]);
    fsacc[5] = fmaf(a, v.y, fsacc[5]);
    fsacc[6] = fmaf(a, v.z, fsacc[6]);
    fsacc[7] = fmaf(a, v.w, fsacc[7]);
  }
  float4* op = (float4*)(p1part + ((b*2+ob)*512 + m)*8);
  op[0] = make_float4(fsacc[0],fsacc[1],fsacc[2],fsacc[3]);
  op[1] = make_float4(fsacc[4],fsacc[5],fsacc[6],fsacc[7]);
}

// pointconv2 (11->128, maxpool over 16 NN), DOUBLE-FACTORIZED (r11 proven),
// WITH THE FINAL @We+be MEAN FUSED via the r13-VALIDATED last-block pattern:
//   h[o] = PP2_j[o] - Q_m[o],  PP2_j = bc + f_j.Wc[3:11] + p_j.Wc[0:3],
//   f_j = lrelu(p1part_half0 + p1part_half1 + bs).
// Each of the batch's 4 o-blocks release-stores its 32-float slice (agent
// scope -- cross-XCD safe) and bumps a per-batch counter; the block seeing
// old==3 acquire-loads all 128 and computes out[b][:].  cnt is zeroed by a
// stream-ordered hipMemsetAsync (captured into the graph, re-run per replay).
__global__ __attribute__((amdgpu_flat_work_group_size(512,512), amdgpu_waves_per_eu(4,4)))
void feat2_kernel(const float4* __restrict__ cand,
    const float* __restrict__ p1part, const int* __restrict__ idx2,
    const float* __restrict__ Wc, const float* __restrict__ bc,
    const float* __restrict__ bs,
    const float* __restrict__ We, const float* __restrict__ beF,
    float* __restrict__ p2red, unsigned int* __restrict__ cnt,
    float* __restrict__ out)
{
  __shared__ float sP2[512*32];                    // 64 KB, swizzled 16B slots
  __shared__ float sred[32];
  __shared__ float sfin[128];
  __shared__ int sLast;
  const int bx = blockIdx.x;                       // 0..1023
  const int b = bx >> 2, ob = bx & 3;              // batch, o-block (32 outputs)
  const int o_base = ob*32;
  const int tid = threadIdx.x;
  const float4* __restrict__ cb = cand + b*1024;
  if (tid < 32) sred[tid] = 0.f;

  // ---- phase 0: f_j = lrelu(pa+pb+bs); PP2_j = bc + f_j@Wc[3:11] + p_j@Wc[0:3] ----
  { const float4* __restrict__ pa4 = (const float4*)(p1part + ((b*2+0)*512 + tid)*8);
    const float4* __restrict__ pb4 = (const float4*)(p1part + ((b*2+1)*512 + tid)*8);
    float4 a0 = pa4[0], a1 = pa4[1], c0 = pb4[0], c1 = pb4[1];
    float4 s0 = *(const float4*)(bs), s1 = *(const float4*)(bs+4);
    float f[8];
    f[0]=lrelu(a0.x+c0.x+s0.x); f[1]=lrelu(a0.y+c0.y+s0.y);
    f[2]=lrelu(a0.z+c0.z+s0.z); f[3]=lrelu(a0.w+c0.w+s0.w);
    f[4]=lrelu(a1.x+c1.x+s1.x); f[5]=lrelu(a1.y+c1.y+s1.y);
    f[6]=lrelu(a1.z+c1.z+s1.z); f[7]=lrelu(a1.w+c1.w+s1.w);
    float4 cj = cb[2*tid];                         // xyz1 point j = cand[2j]
    float* row = sP2 + tid*32;
    const int sw = (tid & 7);
#pragma unroll
    for (int o4=0;o4<8;o4++){
      float4 s = *(const float4*)(bc + o_base + o4*4);   // bias folded in
      { float4 wa = *(const float4*)(Wc +        o_base + o4*4);  // xyz rows
        float4 wb = *(const float4*)(Wc + 128  + o_base + o4*4);
        float4 wc = *(const float4*)(Wc + 256  + o_base + o4*4);
        s.x = fmaf(cj.x,wa.x, fmaf(cj.y,wb.x, fmaf(cj.z,wc.x, s.x)));
        s.y = fmaf(cj.x,wa.y, fmaf(cj.y,wb.y, fmaf(cj.z,wc.y, s.y)));
        s.z = fmaf(cj.x,wa.z, fmaf(cj.y,wb.z, fmaf(cj.z,wc.z, s.z)));
        s.w = fmaf(cj.x,wa.w, fmaf(cj.y,wb.w, fmaf(cj.z,wc.w, s.w))); }
#pragma unroll
      for (int c=0;c<8;c++){
        float4 w = *(const float4*)(Wc + (3+c)*128 + o_base + o4*4); // uniform
        s.x = fmaf(f[c], w.x, s.x);
        s.y = fmaf(f[c], w.y, s.y);
        s.z = fmaf(f[c], w.z, s.z);
        s.w = fmaf(f[c], w.w, s.w);
      }
      *(float4*)(row + ((o4 ^ sw) << 2)) = s;            // swizzled 16B slot
    }
  }
  __syncthreads();

  // ---- main: thread (m = tid>>2, oq = tid&3) -> query m, 8 outputs ----
  const int m = tid >> 2, oq = tid & 3;            // 128 queries x 4 o-quads
  const float4 qv = cb[8*m];                       // xyz2 query = cand[8m]
  float Q[8];
  { const int og = o_base + oq*8;
#pragma unroll
    for (int i=0;i<2;i++){
      float4 a = *(const float4*)(Wc +        og + i*4);
      float4 bb= *(const float4*)(Wc + 128  + og + i*4);
      float4 cc= *(const float4*)(Wc + 256  + og + i*4);
      Q[i*4+0] = fmaf(qv.x,a.x, fmaf(qv.y,bb.x, qv.z*cc.x));
      Q[i*4+1] = fmaf(qv.x,a.y, fmaf(qv.y,bb.y, qv.z*cc.y));
      Q[i*4+2] = fmaf(qv.x,a.z, fmaf(qv.y,bb.z, qv.z*cc.z));
      Q[i*4+3] = fmaf(qv.x,a.w, fmaf(qv.y,bb.w, qv.z*cc.w));
    } }
  int idxr[16];
  { const int4* ip = (const int4*)(idx2 + (b*128+m)*16);
    int4 a=ip[0], b2=ip[1], c2=ip[2], d2=ip[3];
    idxr[0]=a.x; idxr[1]=a.y; idxr[2]=a.z; idxr[3]=a.w;
    idxr[4]=b2.x; idxr[5]=b2.y; idxr[6]=b2.z; idxr[7]=b2.w;
    idxr[8]=c2.x; idxr[9]=c2.y; idxr[10]=c2.z; idxr[11]=c2.w;
    idxr[12]=d2.x; idxr[13]=d2.y; idxr[14]=d2.z; idxr[15]=d2.w; }

  float acc[8];
#pragma unroll
  for (int o=0;o<8;o++) acc[o] = -FLT_MAX;

#pragma unroll 4
  for (int k=0;k<16;k++){
    const int j = idxr[k];
    const float* row = sP2 + j*32;
    const int sw = (j & 7);
    float4 p0 = *(const float4*)(row + (((2*oq  ) ^ sw) << 2));
    float4 p1 = *(const float4*)(row + (((2*oq+1) ^ sw) << 2));
    acc[0] = fmaxf(acc[0], p0.x - Q[0]);
    acc[1] = fmaxf(acc[1], p0.y - Q[1]);
    acc[2] = fmaxf(acc[2], p0.z - Q[2]);
    acc[3] = fmaxf(acc[3], p0.w - Q[3]);
    acc[4] = fmaxf(acc[4], p1.x - Q[4]);
    acc[5] = fmaxf(acc[5], p1.y - Q[5]);
    acc[6] = fmaxf(acc[6], p1.z - Q[6]);
    acc[7] = fmaxf(acc[7], p1.w - Q[7]);
  }

  // lrelu once per output, then mean over queries: shfl-reduce the 16 m's in
  // this wave (lane bits 2..5), one atomic per (wave, oq, o).
#pragma unroll
  for (int o=0;o<8;o++){
    float v = fmaxf(acc[o], 0.2f*acc[o]);
    v += __shfl_xor(v, 4);
    v += __shfl_xor(v, 8);
    v += __shfl_xor(v, 16);
    v += __shfl_xor(v, 32);
    if ((threadIdx.x & 60) == 0)                   // lanes 0..3, one per oq
      atomicAdd(&sred[oq*8+o], v);
  }
  __syncthreads();

  // ---- fused final: last block of this batch applies @We + beF, /128 ----
  if (tid < 32)
    __hip_atomic_store(&p2red[b*128 + o_base + tid], sred[tid],
                       __ATOMIC_RELEASE, __HIP_MEMORY_SCOPE_AGENT);
  __syncthreads();                                 // drains stores before tid0 proceeds
  if (tid == 0){
    unsigned old = __hip_atomic_fetch_add(&cnt[b], 1u,
                       __ATOMIC_ACQ_REL, __HIP_MEMORY_SCOPE_AGENT);
    sLast = (old == 3u) ? 1 : 0;                   // cnt zeroed per launch -> truly last
  }
  __syncthreads();
  if (sLast){
    if (tid < 128)
      sfin[tid] = __hip_atomic_load(&p2red[b*128 + tid],
                       __ATOMIC_ACQUIRE, __HIP_MEMORY_SCOPE_AGENT);
    __syncthreads();
    if (tid < 256){
      float s = 0.f;
#pragma unroll 8
      for (int c=0;c<128;c++) s += sfin[c]*We[c*256+tid];
      out[b*256+tid] = beF[tid] + s*0.0078125f;    // mean over 128 queries
    }
  }
}

extern "C" void kernel_launch(void* const* d_in, const int* in_sizes, int n_in,
                              void* d_out, int out_size, void* d_ws, size_t ws_size,
                              hipStream_t stream) {
  (void)in_sizes; (void)n_in; (void)out_size; (void)ws_size;
  const float* pc   = (const float*)d_in[0];
  const float* W0   = (const float*)d_in[1];
  const float* b0   = (const float*)d_in[2];
  const float* g0   = (const float*)d_in[3];
  const float* be0  = (const float*)d_in[4];
  const float* W1   = (const float*)d_in[5];
  const float* b1   = (const float*)d_in[6];
  const float* g1   = (const float*)d_in[7];
  const float* be1  = (const float*)d_in[8];
  const float* pcW  = (const float*)d_in[9];
  const float* pcb  = (const float*)d_in[10];
  const float* Ws   = (const float*)d_in[11];
  const float* bs   = (const float*)d_in[12];
  const float* Wc   = (const float*)d_in[13];
  const float* bc   = (const float*)d_in[14];
  const float* We   = (const float*)d_in[15];
  const float* beF  = (const float*)d_in[16];

  char* ws = (char*)d_ws;
  float4* cand0 = (float4*)ws;                        // 0-4 MB
  float*  feats = (float*)(ws + (4u<<20));            // 4-20 MB
  int*    idx1  = (int*)  (ws + (20u<<20));           // 20-28 MB
  int*    idx2  = (int*)  (ws + (28u<<20));           // 28-30 MB
  float*  p1part= (float*)(ws + (30u<<20));           // 30-38 MB
  float*  p2red = (float*)(ws + (38u<<20));           // 128 KB
  unsigned int* cnt = (unsigned int*)(ws + (38u<<20) + (256u<<10)); // 1 KB
  float*  out   = (float*)d_out;

  // Stream-ordered zeroing of the per-batch arrival counters (graph-captured,
  // re-executed every replay -> counter starts at 0 each iteration).
  hipMemsetAsync(cnt, 0, 256*sizeof(unsigned int), stream);

  prep_kernel<<<1024, 256, 0, stream>>>(pc, W0,b0,g0,be0, W1,b1,g1,be1, cand0, feats);
  knn_fused_kernel<<<512, 1024, 0, stream>>>(cand0, idx1, idx2);
  feat1_kernel<<<512, 512, 0, stream>>>(cand0, feats, idx1, pcW, pcb, Ws, p1part);
  feat2_kernel<<<1024, 512, 0, stream>>>(cand0, p1part, idx2, Wc, bc, bs,
                                         We, beF, p2red, cnt, out);
}

// Round 15
// 211.153 us; speedup vs baseline: 1.2060x; 1.1581x over previous
//
#include <hip/hip_runtime.h>
#include <float.h>
#include <math.h>

#define LEAK 0.2f
#define EPS 1e-5f

__device__ __forceinline__ float lrelu(float v){ return v > 0.f ? v : LEAK*v; }

__device__ __forceinline__ void ln_lrelu16(float* h, const float* __restrict__ g, const float* __restrict__ be){
  float mu = 0.f;
#pragma unroll
  for (int o=0;o<16;o++) mu += h[o];
  mu *= 0.0625f;
  float var = 0.f;
#pragma unroll
  for (int o=0;o<16;o++){ float d = h[o]-mu; var += d*d; }
  var *= 0.0625f;
  float rs = 1.0f / sqrtf(var + EPS);
#pragma unroll
  for (int o=0;o<16;o++){ float v = (h[o]-mu)*rs*g[o] + be[o]; h[o] = lrelu(v); }
}

// Stage 1: per-point candidate float4 (x,y,z,|p|^2) + 3->16->16 MLP w/ LN+lrelu.
// KEEP SEPARATE: inlining into knn doubled knn's VGPR 32->64 (+21 us, r13);
// inlining into feat1's phase 0 cost more than the saved launch (r13).
__global__ __launch_bounds__(256) void prep_kernel(const float* __restrict__ pc,
    const float* __restrict__ W0, const float* __restrict__ b0, const float* __restrict__ g0, const float* __restrict__ be0,
    const float* __restrict__ W1, const float* __restrict__ b1, const float* __restrict__ g1, const float* __restrict__ be1,
    float4* __restrict__ cand, float* __restrict__ feats)
{
  const int p = blockIdx.x*256 + threadIdx.x;      // 0 .. 256*1024-1
  const int b = p >> 10, n = p & 1023;
  const float* base = pc + b*3072;
  const float x = base[n], y = base[1024+n], z = base[2048+n];
  cand[p] = make_float4(x, y, z, x*x + y*y + z*z);
  float h[16];
#pragma unroll
  for (int o=0;o<16;o++) h[o] = b0[o] + x*W0[o] + y*W0[16+o] + z*W0[32+o];
  ln_lrelu16(h, g0, be0);
  float h2[16];
#pragma unroll
  for (int o=0;o<16;o++){
    float s = b1[o];
#pragma unroll
    for (int c=0;c<16;c++) s += h[c]*W1[c*16+o];
    h2[o] = s;
  }
  ln_lrelu16(h2, g1, be1);
  float4* fo = (float4*)(feats + p*16);
  fo[0] = make_float4(h2[0],h2[1],h2[2],h2[3]);
  fo[1] = make_float4(h2[4],h2[5],h2[6],h2[7]);
  fo[2] = make_float4(h2[8],h2[9],h2[10],h2[11]);
  fo[3] = make_float4(h2[12],h2[13],h2[14],h2[15]);
}

// ---- packed top-k keys: ordered-uint(distance) with 10 index bits in the LSBs.
#define KNN_SENT 0xFF7FFC00u   // enc_key(FLT_MAX, 0): finite, larger than any real key
__device__ __forceinline__ unsigned enc_key(float d, int n){
  unsigned u = __float_as_uint(d);
  u ^= (unsigned)(((int)u) >> 31) | 0x80000000u;   // total-order transform
  return (u & ~1023u) | (unsigned)n;
}
__device__ __forceinline__ float dec_key(unsigned k){
  unsigned u = k ^ ((unsigned)(~(((int)k) >> 31)) | 0x80000000u);
  return __uint_as_float(u);
}

__device__ __forceinline__ unsigned med3u(unsigned a, unsigned b, unsigned c){
  unsigned d;
  asm("v_med3_u32 %0, %1, %2, %3" : "=v"(d) : "v"(a), "v"(b), "v"(c));
  return d;
}

// Insert into ASCENDING sorted dk[16], dropping the max.
// new[j] = median(old[j-1], old[j], key): computed DOWNWARD so old[j-1] is
// still unmodified -> 16 independent v_med3_u32 (1 VALU/slot, no serial chain).
// key >= dk[15] is a mathematical no-op (self-reject); keys unique (index LSBs).
__device__ __forceinline__ void ins_sorted(unsigned (&dk)[16], unsigned key){
#pragma unroll
  for (int j=15;j>0;--j) dk[j] = med3u(dk[j-1], dk[j], key);
  dk[0] = key < dk[0] ? key : dk[0];
}

// KNN top-16 body (r8/r10 measured optimum: ~72.5 us @ ~100% VALUBusy,
// VGPR 32, occ 76% -- structurally closed).  Candidates staged in LDS;
// chunk 0 = 32 unconditional inserts + 32 via single-u32 flag/drain;
// chunks 1.. = u64 flag+drain with per-64 Tf refresh.  Merge: log-tree of
// ins-merges, final level via reversed elementwise min.
template<int QS, int CS, int NQTOT, int NQ, int SPLIT, int NCAND>
__device__ __forceinline__ void knn_body(unsigned* md, float4* scand,
    const float4* __restrict__ cand, int bid, int* __restrict__ idx_out)
{
  constexpr int NC = NCAND / SPLIT;                // candidates per thread
  constexpr int QG = NQTOT / NQ;                   // blocks per batch
  constexpr int W  = SPLIT*NQ;                     // md width
  constexpr int QSL = QS / CS;                     // query stride in staged space
  const int b = bid / QG, qg = bid % QG;
  const int tid = threadIdx.x;
  const int m = tid & (NQ-1), s = tid / NQ;        // s is wave-uniform (NQ % 64 == 0)
  const int mg = qg*NQ + m;                        // global query id
  const float4* __restrict__ cb = cand + b*1024;

  for (int i = tid; i < NCAND; i += NQ*SPLIT)
    scand[i] = cb[i*CS];
  __syncthreads();

  const float4 qv = scand[mg*QSL];
  const float qx2=-2.f*qv.x, qy2=-2.f*qv.y, qz2=-2.f*qv.z;
  const int n0u = __builtin_amdgcn_readfirstlane(s*NC);   // uniform candidate base

  unsigned dk[16];
#pragma unroll
  for (int j=0;j<16;j++) dk[j] = KNN_SENT;

  // fill: first 32 candidates unconditional (no flag, no divergence).
#pragma unroll 8
  for (int t=0;t<32;t++){
    float4 c = scand[n0u+t];
    float d = fmaf(c.x,qx2, fmaf(c.y,qy2, fmaf(c.z,qz2, c.w)));
    ins_sorted(dk, enc_key(d, n0u+t));
  }
  float Tf = dec_key(dk[15]);

  // rest of chunk 0 (t=32..63): single u32 flag+drain.
  {
    unsigned m32 = 0u;
#pragma unroll 8
    for (int t=32;t<64;t++){
      float4 c = scand[n0u+t];
      float d = fmaf(c.x,qx2, fmaf(c.y,qy2, fmaf(c.z,qz2, c.w)));
      if (d < Tf) m32 |= (1u<<(t-32));
    }
    while (m32){
      const int t = __builtin_ctz(m32) + 32;
      m32 &= m32-1u;
      float4 c = scand[n0u+t];
      float d = fmaf(c.x,qx2, fmaf(c.y,qy2, fmaf(c.z,qz2, c.w)));
      ins_sorted(dk, enc_key(d, n0u+t));
    }
    Tf = dec_key(dk[15]);
  }

  for (int ch=1; ch<NC/64; ch++){
    const int cb0u = n0u + ch*64;                  // uniform
    unsigned long long msk = 0ull;
#pragma unroll 16
    for (int t=0;t<64;t++){
      float4 c = scand[cb0u+t];
      float d = fmaf(c.x,qx2, fmaf(c.y,qy2, fmaf(c.z,qz2, c.w)));
      if (d < Tf) msk |= (1ull<<t);
    }
    while (msk){
      const int t = __builtin_ctzll(msk);
      msk &= msk-1ull;
      float4 c = scand[cb0u+t];
      float d = fmaf(c.x,qx2, fmaf(c.y,qy2, fmaf(c.z,qz2, c.w)));
      ins_sorted(dk, enc_key(d, cb0u+t));
    }
    Tf = dec_key(dk[15]);
  }

  // ---- log-tree merge across splits ----
  if constexpr (SPLIT > 1){
    if (s > 0){
      const int col = s*NQ + m;
#pragma unroll
      for (int j=0;j<16;j++) md[j*W + col] = dk[j];
    }
#pragma unroll
    for (int step = SPLIT/2; step > 1; step >>= 1){
      __syncthreads();
      if (s < step){
        const int col2 = (s+step)*NQ + m;
#pragma unroll
        for (int j=0;j<16;j++) ins_sorted(dk, md[j*W + col2]);
        if (s > 0){
          const int col = s*NQ + m;
#pragma unroll
          for (int j=0;j<16;j++) md[j*W + col] = dk[j];
        }
      }
    }
    __syncthreads();
    if (s != 0) return;
    // final: both lists sorted ascending -> 16 smallest of union is
    // elementwise min with the other list reversed (result unsorted - fine).
    const int col2 = NQ + m;
#pragma unroll
    for (int j=0;j<16;j++){
      unsigned o = md[(15-j)*W + col2];
      dk[j] = o < dk[j] ? o : dk[j];
    }
  }

  int ik[16];
#pragma unroll
  for (int j=0;j<16;j++) ik[j] = (int)(dk[j] & 1023u);
  int4* op = (int4*)(idx_out + (b*NQTOT + mg)*16);
  op[0] = make_int4(ik[0],ik[1],ik[2],ik[3]);
  op[1] = make_int4(ik[4],ik[5],ik[6],ik[7]);
  op[2] = make_int4(ik[8],ik[9],ik[10],ik[11]);
  op[3] = make_int4(ik[12],ik[13],ik[14],ik[15]);
}

// Fused knn, r8 geometry: 1024-thr blocks; blocks 0..255 = knn1 (512 q,
// SPLIT=2), blocks 256..511 = knn2 (128 q, SPLIT=8).  80 KB union -> 2
// blocks/CU, 32 waves/CU; measured ~76% occ / ~100% VALUBusy.
__global__ __attribute__((amdgpu_flat_work_group_size(1024,1024), amdgpu_waves_per_eu(4,8)))
void knn_fused_kernel(const float4* __restrict__ cand,
                      int* __restrict__ idx1, int* __restrict__ idx2)
{
  __shared__ __align__(16) char smem[81920];       // 64 KB md + 16 KB scand
  unsigned* md = (unsigned*)smem;
  if (blockIdx.x < 256){
    float4* scand = (float4*)(smem + 65536);
    knn_body<2,1,512,512,2,1024>(md, scand, cand, blockIdx.x, idx1);
  } else {
    float4* scand = (float4*)(smem + 65536);
    knn_body<8,2,128,128,8,512>(md, scand, cand, blockIdx.x - 256, idx2);
  }
}

// pointconv1 (19->32, maxpool over 16 NN), DOUBLE-FACTORIZED:
//   h[o] = PP_j[o] - Q_m[o],
//   PP_j = Wb + f_j.W[3:19] + p_j.W[0:3]  (phase 0),  Q_m = q_m.W[0:3].
// Inner body 1 SUB + 1 MAX.  P transposed in LDS (sPT[o][j], b32 gather,
// one vaddr + imm offsets, ~conflict-free).  2 o-halves/batch, 64 KB ->
// 2 blocks/CU.  Epilogue: partial fs (feat2 fuses lrelu(p0+p1+bs)).
__global__ __attribute__((amdgpu_flat_work_group_size(512,512), amdgpu_waves_per_eu(4,4)))
void feat1_kernel(const float4* __restrict__ cand,
    const float* __restrict__ feats, const int* __restrict__ idx1,
    const float* __restrict__ W, const float* __restrict__ Wb,
    const float* __restrict__ Ws,
    float* __restrict__ p1part)
{
  __shared__ float sPT[16*1024];                   // 64 KB, o-major
  const int bx = blockIdx.x;
  const int b = bx >> 1, ob = bx & 1;              // batch, o-half
  const int ob16 = ob*16;
  const int tid = threadIdx.x;
  const float4* __restrict__ cb = cand + b*1024;
  const float4* __restrict__ fb4 = (const float4*)(feats + b*16384);

  // ---- phase 0: PP_j over this block's 16 o's, 2 points per thread ----
#pragma unroll
  for (int i=0;i<2;i++){
    const int j = tid + i*512;
    float4 cj = cb[j];                             // point xyz (w unused)
    float4 f0 = fb4[j*4+0], f1 = fb4[j*4+1], f2 = fb4[j*4+2], f3 = fb4[j*4+3];
    float f[16] = {f0.x,f0.y,f0.z,f0.w, f1.x,f1.y,f1.z,f1.w,
                   f2.x,f2.y,f2.z,f2.w, f3.x,f3.y,f3.z,f3.w};
#pragma unroll
    for (int o4=0;o4<4;o4++){
      float4 s = *(const float4*)(Wb + ob16 + o4*4);   // bias folded in
      { float4 wa = *(const float4*)(W +       ob16 + o4*4);   // xyz rows folded
        float4 wb = *(const float4*)(W + 32  + ob16 + o4*4);
        float4 wc = *(const float4*)(W + 64  + ob16 + o4*4);
        s.x = fmaf(cj.x,wa.x, fmaf(cj.y,wb.x, fmaf(cj.z,wc.x, s.x)));
        s.y = fmaf(cj.x,wa.y, fmaf(cj.y,wb.y, fmaf(cj.z,wc.y, s.y)));
        s.z = fmaf(cj.x,wa.z, fmaf(cj.y,wb.z, fmaf(cj.z,wc.z, s.z)));
        s.w = fmaf(cj.x,wa.w, fmaf(cj.y,wb.w, fmaf(cj.z,wc.w, s.w))); }
#pragma unroll
      for (int c=0;c<16;c++){
        float4 w = *(const float4*)(W + (3+c)*32 + ob16 + o4*4);  // uniform
        s.x = fmaf(f[c], w.x, s.x);
        s.y = fmaf(f[c], w.y, s.y);
        s.z = fmaf(f[c], w.z, s.z);
        s.w = fmaf(f[c], w.w, s.w);
      }
      sPT[(o4*4+0)*1024 + j] = s.x;                // coalesced column writes
      sPT[(o4*4+1)*1024 + j] = s.y;
      sPT[(o4*4+2)*1024 + j] = s.z;
      sPT[(o4*4+3)*1024 + j] = s.w;
    }
  }
  __syncthreads();

  // ---- main: per query, Q_m once, then 16 neighbors x 16 outputs ----
  const int m = tid;
  const float4 qv = cb[2*m];                       // query xyz
  float Q[16];
#pragma unroll
  for (int i=0;i<4;i++){
    float4 a = *(const float4*)(W +       ob16 + i*4);
    float4 bb= *(const float4*)(W + 32  + ob16 + i*4);
    float4 cc= *(const float4*)(W + 64  + ob16 + i*4);
    Q[i*4+0] = fmaf(qv.x,a.x, fmaf(qv.y,bb.x, qv.z*cc.x));
    Q[i*4+1] = fmaf(qv.x,a.y, fmaf(qv.y,bb.y, qv.z*cc.y));
    Q[i*4+2] = fmaf(qv.x,a.z, fmaf(qv.y,bb.z, qv.z*cc.z));
    Q[i*4+3] = fmaf(qv.x,a.w, fmaf(qv.y,bb.w, qv.z*cc.w));
  }
  int idxr[16];
  { const int4* ip = (const int4*)(idx1 + (b*512+m)*16);
    int4 a=ip[0], b2=ip[1], c2=ip[2], d2=ip[3];
    idxr[0]=a.x; idxr[1]=a.y; idxr[2]=a.z; idxr[3]=a.w;
    idxr[4]=b2.x; idxr[5]=b2.y; idxr[6]=b2.z; idxr[7]=b2.w;
    idxr[8]=c2.x; idxr[9]=c2.y; idxr[10]=c2.z; idxr[11]=c2.w;
    idxr[12]=d2.x; idxr[13]=d2.y; idxr[14]=d2.z; idxr[15]=d2.w; }

  float acc[16];
#pragma unroll
  for (int o=0;o<16;o++) acc[o] = -FLT_MAX;

#pragma unroll 4
  for (int k=0;k<16;k++){
    const int j = idxr[k];
    const float* pj = sPT + j;                     // one vaddr, 16 imm offsets
#pragma unroll
    for (int o=0;o<16;o++)
      acc[o] = fmaxf(acc[o], pj[o*1024] - Q[o]);   // 1 sub + 1 max
  }

  float fsacc[8] = {0.f,0.f,0.f,0.f,0.f,0.f,0.f,0.f};
#pragma unroll
  for (int o=0;o<16;o++){
    const float a = fmaxf(acc[o], 0.2f*acc[o]);    // lrelu once per output
    float4 u = *(const float4*)(Ws + (ob16+o)*8);  // uniform -> s_load
    float4 v = *(const float4*)(Ws + (ob16+o)*8 + 4);
    fsacc[0] = fmaf(a, u.x, fsacc[0]);
    fsacc[1] = fmaf(a, u.y, fsacc[1]);
    fsacc[2] = fmaf(a, u.z, fsacc[2]);
    fsacc[3] = fmaf(a, u.w, fsacc[3]);
    fsacc[4] = fmaf(a, v.x, fsacc[4]);
    fsacc[5] = fmaf(a, v.y, fsacc[5]);
    fsacc[6] = fmaf(a, v.z, fsacc[6]);
    fsacc[7] = fmaf(a, v.w, fsacc[7]);
  }
  float4* op = (float4*)(p1part + ((b*2+ob)*512 + m)*8);
  op[0] = make_float4(fsacc[0],fsacc[1],fsacc[2],fsacc[3]);
  op[1] = make_float4(fsacc[4],fsacc[5],fsacc[6],fsacc[7]);
}

// pointconv2 (11->128, maxpool over 16 NN), DOUBLE-FACTORIZED:
//   h[o] = PP2_j[o] - Q_m[o],  PP2_j = bc + f_j.Wc[3:11] + p_j.Wc[0:3],
//   f_j = lrelu(p1part_half0 + p1part_half1 + bs) fused in phase 0.
// Output range split across 4 blocks of 32 (64 KB P2 tile -> 2 blocks/CU).
// Plain stores to p2red; SEPARATE final_kernel (last-block fusion with
// agent-scope atomics measured +32 us: per-block cross-XCD coherence
// flushes thrash caches -- r14).
__global__ __attribute__((amdgpu_flat_work_group_size(512,512), amdgpu_waves_per_eu(4,4)))
void feat2_kernel(const float4* __restrict__ cand,
    const float* __restrict__ p1part, const int* __restrict__ idx2,
    const float* __restrict__ Wc, const float* __restrict__ bc,
    const float* __restrict__ bs,
    float* __restrict__ p2red)
{
  __shared__ float sP2[512*32];                    // 64 KB, swizzled 16B slots
  __shared__ float sred[32];
  const int bx = blockIdx.x;                       // 0..1023
  const int b = bx >> 2, ob = bx & 3;              // batch, o-block (32 outputs)
  const int o_base = ob*32;
  const int tid = threadIdx.x;
  const float4* __restrict__ cb = cand + b*1024;
  if (tid < 32) sred[tid] = 0.f;

  // ---- phase 0: f_j = lrelu(pa+pb+bs); PP2_j = bc + f_j@Wc[3:11] + p_j@Wc[0:3] ----
  { const float4* __restrict__ pa4 = (const float4*)(p1part + ((b*2+0)*512 + tid)*8);
    const float4* __restrict__ pb4 = (const float4*)(p1part + ((b*2+1)*512 + tid)*8);
    float4 a0 = pa4[0], a1 = pa4[1], c0 = pb4[0], c1 = pb4[1];
    float4 s0 = *(const float4*)(bs), s1 = *(const float4*)(bs+4);
    float f[8];
    f[0]=lrelu(a0.x+c0.x+s0.x); f[1]=lrelu(a0.y+c0.y+s0.y);
    f[2]=lrelu(a0.z+c0.z+s0.z); f[3]=lrelu(a0.w+c0.w+s0.w);
    f[4]=lrelu(a1.x+c1.x+s1.x); f[5]=lrelu(a1.y+c1.y+s1.y);
    f[6]=lrelu(a1.z+c1.z+s1.z); f[7]=lrelu(a1.w+c1.w+s1.w);
    float4 cj = cb[2*tid];                         // xyz1 point j = cand[2j]
    float* row = sP2 + tid*32;
    const int sw = (tid & 7);
#pragma unroll
    for (int o4=0;o4<8;o4++){
      float4 s = *(const float4*)(bc + o_base + o4*4);   // bias folded in
      { float4 wa = *(const float4*)(Wc +        o_base + o4*4);  // xyz rows
        float4 wb = *(const float4*)(Wc + 128  + o_base + o4*4);
        float4 wc = *(const float4*)(Wc + 256  + o_base + o4*4);
        s.x = fmaf(cj.x,wa.x, fmaf(cj.y,wb.x, fmaf(cj.z,wc.x, s.x)));
        s.y = fmaf(cj.x,wa.y, fmaf(cj.y,wb.y, fmaf(cj.z,wc.y, s.y)));
        s.z = fmaf(cj.x,wa.z, fmaf(cj.y,wb.z, fmaf(cj.z,wc.z, s.z)));
        s.w = fmaf(cj.x,wa.w, fmaf(cj.y,wb.w, fmaf(cj.z,wc.w, s.w))); }
#pragma unroll
      for (int c=0;c<8;c++){
        float4 w = *(const float4*)(Wc + (3+c)*128 + o_base + o4*4); // uniform
        s.x = fmaf(f[c], w.x, s.x);
        s.y = fmaf(f[c], w.y, s.y);
        s.z = fmaf(f[c], w.z, s.z);
        s.w = fmaf(f[c], w.w, s.w);
      }
      *(float4*)(row + ((o4 ^ sw) << 2)) = s;            // swizzled 16B slot
    }
  }
  __syncthreads();

  // ---- main: thread (m = tid>>2, oq = tid&3) -> query m, 8 outputs ----
  const int m = tid >> 2, oq = tid & 3;            // 128 queries x 4 o-quads
  const float4 qv = cb[8*m];                       // xyz2 query = cand[8m]
  float Q[8];
  { const int og = o_base + oq*8;
#pragma unroll
    for (int i=0;i<2;i++){
      float4 a = *(const float4*)(Wc +        og + i*4);
      float4 bb= *(const float4*)(Wc + 128  + og + i*4);
      float4 cc= *(const float4*)(Wc + 256  + og + i*4);
      Q[i*4+0] = fmaf(qv.x,a.x, fmaf(qv.y,bb.x, qv.z*cc.x));
      Q[i*4+1] = fmaf(qv.x,a.y, fmaf(qv.y,bb.y, qv.z*cc.y));
      Q[i*4+2] = fmaf(qv.x,a.z, fmaf(qv.y,bb.z, qv.z*cc.z));
      Q[i*4+3] = fmaf(qv.x,a.w, fmaf(qv.y,bb.w, qv.z*cc.w));
    } }
  int idxr[16];
  { const int4* ip = (const int4*)(idx2 + (b*128+m)*16);
    int4 a=ip[0], b2=ip[1], c2=ip[2], d2=ip[3];
    idxr[0]=a.x; idxr[1]=a.y; idxr[2]=a.z; idxr[3]=a.w;
    idxr[4]=b2.x; idxr[5]=b2.y; idxr[6]=b2.z; idxr[7]=b2.w;
    idxr[8]=c2.x; idxr[9]=c2.y; idxr[10]=c2.z; idxr[11]=c2.w;
    idxr[12]=d2.x; idxr[13]=d2.y; idxr[14]=d2.z; idxr[15]=d2.w; }

  float acc[8];
#pragma unroll
  for (int o=0;o<8;o++) acc[o] = -FLT_MAX;

#pragma unroll 4
  for (int k=0;k<16;k++){
    const int j = idxr[k];
    const float* row = sP2 + j*32;
    const int sw = (j & 7);
    float4 p0 = *(const float4*)(row + (((2*oq  ) ^ sw) << 2));
    float4 p1 = *(const float4*)(row + (((2*oq+1) ^ sw) << 2));
    acc[0] = fmaxf(acc[0], p0.x - Q[0]);
    acc[1] = fmaxf(acc[1], p0.y - Q[1]);
    acc[2] = fmaxf(acc[2], p0.z - Q[2]);
    acc[3] = fmaxf(acc[3], p0.w - Q[3]);
    acc[4] = fmaxf(acc[4], p1.x - Q[4]);
    acc[5] = fmaxf(acc[5], p1.y - Q[5]);
    acc[6] = fmaxf(acc[6], p1.z - Q[6]);
    acc[7] = fmaxf(acc[7], p1.w - Q[7]);
  }

  // lrelu once per output, then mean over queries: shfl-reduce the 16 m's in
  // this wave (lane bits 2..5), one atomic per (wave, oq, o).
#pragma unroll
  for (int o=0;o<8;o++){
    float v = fmaxf(acc[o], 0.2f*acc[o]);
    v += __shfl_xor(v, 4);
    v += __shfl_xor(v, 8);
    v += __shfl_xor(v, 16);
    v += __shfl_xor(v, 32);
    if ((threadIdx.x & 60) == 0)                   // lanes 0..3, one per oq
      atomicAdd(&sred[oq*8+o], v);
  }
  __syncthreads();
  if (tid < 32) p2red[b*128 + o_base + tid] = sred[tid];
}

// out[b][o] = beF[o] + (p2red[b] @ We) / 128
__global__ __launch_bounds__(256) void final_kernel(const float* __restrict__ p2red,
    const float* __restrict__ We, const float* __restrict__ beF, float* __restrict__ out)
{
  const int b = blockIdx.x, o = threadIdx.x;
  const float* __restrict__ r0 = p2red + b*128;
  float s = 0.f;
#pragma unroll 8
  for (int c=0;c<128;c++) s += r0[c]*We[c*256+o];
  out[b*256+o] = beF[o] + s*0.0078125f;            // mean over 128 queries
}

extern "C" void kernel_launch(void* const* d_in, const int* in_sizes, int n_in,
                              void* d_out, int out_size, void* d_ws, size_t ws_size,
                              hipStream_t stream) {
  (void)in_sizes; (void)n_in; (void)out_size; (void)ws_size;
  const float* pc   = (const float*)d_in[0];
  const float* W0   = (const float*)d_in[1];
  const float* b0   = (const float*)d_in[2];
  const float* g0   = (const float*)d_in[3];
  const float* be0  = (const float*)d_in[4];
  const float* W1   = (const float*)d_in[5];
  const float* b1   = (const float*)d_in[6];
  const float* g1   = (const float*)d_in[7];
  const float* be1  = (const float*)d_in[8];
  const float* pcW  = (const float*)d_in[9];
  const float* pcb  = (const float*)d_in[10];
  const float* Ws   = (const float*)d_in[11];
  const float* bs   = (const float*)d_in[12];
  const float* Wc   = (const float*)d_in[13];
  const float* bc   = (const float*)d_in[14];
  const float* We   = (const float*)d_in[15];
  const float* beF  = (const float*)d_in[16];

  char* ws = (char*)d_ws;
  float4* cand0 = (float4*)ws;                        // 0-4 MB
  float*  feats = (float*)(ws + (4u<<20));            // 4-20 MB (dead after feat1)
  float*  p2red = (float*)(ws + (4u<<20));            // reuses feats region
  int*    idx1  = (int*)  (ws + (20u<<20));           // 20-28 MB
  int*    idx2  = (int*)  (ws + (28u<<20));           // 28-30 MB
  float*  p1part= (float*)(ws + (30u<<20));           // 30-38 MB
  float*  out   = (float*)d_out;

  prep_kernel<<<1024, 256, 0, stream>>>(pc, W0,b0,g0,be0, W1,b1,g1,be1, cand0, feats);
  knn_fused_kernel<<<512, 1024, 0, stream>>>(cand0, idx1, idx2);
  feat1_kernel<<<512, 512, 0, stream>>>(cand0, feats, idx1, pcW, pcb, Ws, p1part);
  feat2_kernel<<<1024, 512, 0, stream>>>(cand0, p1part, idx2, Wc, bc, bs, p2red);
  final_kernel<<<256, 256, 0, stream>>>(p2red, We, beF, out);
}